// Round 4
// baseline (256.712 us; speedup 1.0000x reference)
//
#include <hip/hip_runtime.h>

// Problem constants (from reference setup_inputs):
//   X:   [B=8, N_old=2048, F=256] fp32
//   A:   [B=8, N_new=4096, N_new=4096] fp32 (pass-through)
//   idx: [B=8, N_old=2048, 1] int32, values in [0, N_new)
// Output: new_X [8,4096,256] fp32 (scatter-add of X rows), then A, concat flat.
//
// Strategy: ONE kernel. Output-row waves invert the scatter into a gather by
// scanning their batch's idx slice (8 KB, L1-resident) with __ballot — no
// workspace, no zero pass, no atomics, no index build. Copy blocks stream A
// with nontemporal loads/stores; parity interleave keeps HBM saturated.

typedef float f32x4 __attribute__((ext_vector_type(4)));

constexpr int B_     = 8;
constexpr int N_OLD  = 2048;
constexpr int N_NEW  = 4096;
constexpr int F_     = 256;

constexpr int ROWS_OUT  = B_ * N_NEW;                             // 32768
constexpr size_t NEWX_ELEMS = (size_t)ROWS_OUT * F_;              // 8,388,608
constexpr size_t A_ELEMS    = (size_t)B_ * N_NEW * (size_t)N_NEW; // 134,217,728
constexpr size_t A_VEC4     = A_ELEMS / 4;                        // 33,554,432

constexpr int GATHER_BLOCKS = ROWS_OUT / 4;   // 8192 (4 waves/block, 1 row/wave)
constexpr int COPY_BLOCKS   = 8192;           // 16 vec4-iters/thread
constexpr int TOTAL_BLOCKS  = GATHER_BLOCKS + COPY_BLOCKS;

__global__ __launch_bounds__(256) void fused_unpool_kernel(
        const f32x4* __restrict__ X4,
        const f32x4* __restrict__ A4,
        const int*   __restrict__ idx,
        f32x4* __restrict__ newX4,
        f32x4* __restrict__ Aout4) {
    if (blockIdx.x & 1) {
        // ---- gather: one output row per wave -------------------------------
        const int gb   = blockIdx.x >> 1;               // 0..8191
        const int wave = threadIdx.x >> 6;
        const int lane = threadIdx.x & 63;
        const int row  = gb * 4 + wave;                 // 0..32767
        const int b    = row >> 12;                     // row / N_NEW
        const int node = row & (N_NEW - 1);
        const int* __restrict__ idxb = idx + b * N_OLD; // 8 KB slice, L1-hot

        f32x4 acc = (f32x4)(0.f);
        #pragma unroll 4
        for (int j = 0; j < N_OLD / 64; ++j) {          // 32 iterations
            const int v = idxb[j * 64 + lane];          // coalesced 256 B
            unsigned long long m = __ballot(v == node); // wave-uniform mask
            while (m) {                                 // expected ~0.5 total/row
                const int k = __builtin_ctzll(m);
                m &= m - 1;
                const int src = b * N_OLD + j * 64 + k; // X row id (ascending)
                acc += X4[(size_t)src * 64 + lane];     // coalesced 1 KB row
            }
        }
        __builtin_nontemporal_store(acc, &newX4[(size_t)row * 64 + lane]);
    } else {
        // ---- streaming A copy: 537 MB each way, > L3 -----------------------
        const size_t cb  = (size_t)(blockIdx.x >> 1);
        size_t i = cb * blockDim.x + threadIdx.x;
        const size_t stride = (size_t)COPY_BLOCKS * 256;
        for (; i < A_VEC4; i += stride) {
            const f32x4 v = __builtin_nontemporal_load(&A4[i]);
            __builtin_nontemporal_store(v, &Aout4[i]);
        }
    }
}

extern "C" void kernel_launch(void* const* d_in, const int* in_sizes, int n_in,
                              void* d_out, int out_size, void* d_ws, size_t ws_size,
                              hipStream_t stream) {
    const f32x4* X4 = (const f32x4*)d_in[0];
    const f32x4* A4 = (const f32x4*)d_in[1];
    const int*  idx = (const int*)d_in[2];

    f32x4* newX4 = (f32x4*)d_out;
    f32x4* Aout4 = (f32x4*)((float*)d_out + NEWX_ELEMS);

    fused_unpool_kernel<<<TOTAL_BLOCKS, 256, 0, stream>>>(X4, A4, idx, newX4, Aout4);
}

// Round 5
// 223.793 us; speedup vs baseline: 1.1471x; 1.1471x over previous
//
#include <hip/hip_runtime.h>

// Problem constants (from reference setup_inputs):
//   X:   [B=8, N_old=2048, F=256] fp32
//   A:   [B=8, N_new=4096, N_new=4096] fp32 (pass-through)
//   idx: [B=8, N_old=2048, 1] int32, values in [0, N_new)
// Output: new_X [8,4096,256] fp32 (scatter-add of X rows), then A, concat flat.
//
// Round-4 structure: memset(counts) -> build inverted index (both tiny) ->
// ONE fused kernel where every block gathers 4 output rows (one per wave,
// via the index) as a prologue and then streams its share of the A copy.
// No segregated gather phase (round-2 flaw), no per-wave idx scan (round-3
// flaw). Copy is 4-deep batched nontemporal for MLP.

typedef float f32x4 __attribute__((ext_vector_type(4)));

constexpr int B_     = 8;
constexpr int N_OLD  = 2048;
constexpr int N_NEW  = 4096;
constexpr int F_     = 256;

constexpr int ROWS_IN   = B_ * N_OLD;                             // 16384
constexpr int ROWS_OUT  = B_ * N_NEW;                             // 32768
constexpr size_t NEWX_ELEMS = (size_t)ROWS_OUT * F_;              // 8,388,608
constexpr size_t A_ELEMS    = (size_t)B_ * N_NEW * (size_t)N_NEW; // 134,217,728
constexpr size_t A_VEC4     = A_ELEMS / 4;                        // 33,554,432

constexpr int CAP = 32;                          // bucket cap (exp. max ~7)
constexpr size_t COUNTS_BYTES  = (size_t)ROWS_OUT * sizeof(int);        // 128 KB
constexpr size_t ENTRIES_BYTES = (size_t)ROWS_OUT * CAP * sizeof(int);  // 4 MB
constexpr size_t WS_NEEDED     = COUNTS_BYTES + ENTRIES_BYTES;

constexpr int    BLOCKS = 8192;                  // 4 rows/block AND copy share
constexpr size_t STRIDE = (size_t)BLOCKS * 256;  // 2,097,152 vec4
constexpr int    ITERS  = (int)(A_VEC4 / STRIDE);// 16 (exact, no remainder)

// ---- index build (tiny prologue dispatches) -----------------------------------

__global__ void build_index_kernel(const int* __restrict__ idx,
                                   int* __restrict__ counts,
                                   int* __restrict__ entries) {
    const int i = blockIdx.x * blockDim.x + threadIdx.x;   // 0..16383
    const int b = i >> 11;                                  // / N_OLD
    const int bin = (b << 12) + idx[i];                     // b*N_NEW + node
    const int pos = atomicAdd(&counts[bin], 1);
    if (pos < CAP) entries[bin * CAP + pos] = i;            // global X row id
}

// ---- fused: per-block gather prologue + streaming A copy ----------------------

__global__ __launch_bounds__(256) void fused_gather_copy_kernel(
        const f32x4* __restrict__ X4,
        const f32x4* __restrict__ A4,
        const int*   __restrict__ counts,
        const int*   __restrict__ entries,
        f32x4* __restrict__ newX4,
        f32x4* __restrict__ Aout4) {
    const int wave = threadIdx.x >> 6;
    const int lane = threadIdx.x & 63;
    const int row  = blockIdx.x * 4 + wave;            // 0..32767, exact cover

    size_t i = (size_t)blockIdx.x * 256 + threadIdx.x;

    // Issue the first copy batch immediately — streaming starts at block start,
    // and the gather's dependent-load chain hides underneath it.
    f32x4 v0 = __builtin_nontemporal_load(&A4[i]);
    f32x4 v1 = __builtin_nontemporal_load(&A4[i +     STRIDE]);
    f32x4 v2 = __builtin_nontemporal_load(&A4[i + 2 * STRIDE]);
    f32x4 v3 = __builtin_nontemporal_load(&A4[i + 3 * STRIDE]);

    // Gather prologue: this wave's output row = sum of its bucket's X rows.
    int c = counts[row];
    if (c > CAP) c = CAP;
    f32x4 acc = (f32x4)(0.f);
    const int* e = &entries[(size_t)row * CAP];
    for (int k = 0; k < c; ++k) {
        acc += X4[(size_t)e[k] * 64 + lane];           // coalesced 1 KB row
    }
    __builtin_nontemporal_store(acc, &newX4[(size_t)row * 64 + lane]);

    // Finish batch 0, then 3 more batches of 4 (16 vec4/thread total).
    __builtin_nontemporal_store(v0, &Aout4[i]);
    __builtin_nontemporal_store(v1, &Aout4[i +     STRIDE]);
    __builtin_nontemporal_store(v2, &Aout4[i + 2 * STRIDE]);
    __builtin_nontemporal_store(v3, &Aout4[i + 3 * STRIDE]);
    i += 4 * STRIDE;

    #pragma unroll
    for (int it = 1; it < ITERS / 4; ++it) {
        f32x4 w0 = __builtin_nontemporal_load(&A4[i]);
        f32x4 w1 = __builtin_nontemporal_load(&A4[i +     STRIDE]);
        f32x4 w2 = __builtin_nontemporal_load(&A4[i + 2 * STRIDE]);
        f32x4 w3 = __builtin_nontemporal_load(&A4[i + 3 * STRIDE]);
        __builtin_nontemporal_store(w0, &Aout4[i]);
        __builtin_nontemporal_store(w1, &Aout4[i +     STRIDE]);
        __builtin_nontemporal_store(w2, &Aout4[i + 2 * STRIDE]);
        __builtin_nontemporal_store(w3, &Aout4[i + 3 * STRIDE]);
        i += 4 * STRIDE;
    }
}

// ---- fallback (round-0 proven) ------------------------------------------------

__global__ void zero_newx_kernel(float4* __restrict__ p, size_t n4) {
    size_t i = (size_t)blockIdx.x * blockDim.x + threadIdx.x;
    size_t stride = (size_t)gridDim.x * blockDim.x;
    const float4 z = make_float4(0.f, 0.f, 0.f, 0.f);
    for (; i < n4; i += stride) p[i] = z;
}

__global__ void scatter_add_kernel(const float* __restrict__ X,
                                   const int* __restrict__ idx,
                                   float* __restrict__ out) {
    const int row = blockIdx.x;
    const int f   = threadIdx.x;
    const int b   = row / N_OLD;
    const int node = idx[row];
    const float v = X[(size_t)row * F_ + f];
    atomicAdd(&out[((size_t)b * N_NEW + node) * (size_t)F_ + f], v);
}

extern "C" void kernel_launch(void* const* d_in, const int* in_sizes, int n_in,
                              void* d_out, int out_size, void* d_ws, size_t ws_size,
                              hipStream_t stream) {
    const float* X   = (const float*)d_in[0];
    const float* A   = (const float*)d_in[1];
    const int*   idx = (const int*)d_in[2];

    float* newX  = (float*)d_out;
    float* A_out = (float*)d_out + NEWX_ELEMS;

    if (ws_size >= WS_NEEDED) {
        int* counts  = (int*)d_ws;
        int* entries = (int*)((char*)d_ws + COUNTS_BYTES);

        // counts must be zero every call (graph replays; ws poisoned once)
        (void)hipMemsetAsync(counts, 0, COUNTS_BYTES, stream);

        build_index_kernel<<<ROWS_IN / 256, 256, 0, stream>>>(idx, counts, entries);

        fused_gather_copy_kernel<<<BLOCKS, 256, 0, stream>>>(
            (const f32x4*)X, (const f32x4*)A, counts, entries,
            (f32x4*)newX, (f32x4*)A_out);
    } else {
        zero_newx_kernel<<<2048, 256, 0, stream>>>((float4*)newX, NEWX_ELEMS / 4);
        scatter_add_kernel<<<ROWS_IN, 256, 0, stream>>>(X, idx, newX);
        (void)hipMemcpyAsync(A_out, A, A_ELEMS * sizeof(float),
                             hipMemcpyDeviceToDevice, stream);
    }
}

// Round 6
// 202.623 us; speedup vs baseline: 1.2669x; 1.1045x over previous
//
#include <hip/hip_runtime.h>

// Problem constants (from reference setup_inputs):
//   X:   [B=8, N_old=2048, F=256] fp32
//   A:   [B=8, N_new=4096, N_new=4096] fp32 (pass-through)
//   idx: [B=8, N_old=2048, 1] int32, values in [0, N_new)
// Output: new_X [8,4096,256] fp32 (scatter-add of X rows), then A, concat flat.
//
// Structure: memset(counts) + build inverted index (tiny) -> ONE fused kernel,
// 1:7 gather:copy block interleave. Copy path is a minimal nt-load/nt-store
// grid-stride loop (low VGPR, full occupancy); gather blocks (2048 x 16 rows)
// hide entirely under the 180 us A-stream.

typedef float f32x4 __attribute__((ext_vector_type(4)));

constexpr int B_     = 8;
constexpr int N_OLD  = 2048;
constexpr int N_NEW  = 4096;
constexpr int F_     = 256;

constexpr int ROWS_IN   = B_ * N_OLD;                             // 16384
constexpr int ROWS_OUT  = B_ * N_NEW;                             // 32768
constexpr size_t NEWX_ELEMS = (size_t)ROWS_OUT * F_;              // 8,388,608
constexpr size_t A_ELEMS    = (size_t)B_ * N_NEW * (size_t)N_NEW; // 134,217,728
constexpr size_t A_VEC4     = A_ELEMS / 4;                        // 33,554,432

constexpr int CAP = 32;                          // bucket cap (exp. max ~7)
constexpr size_t COUNTS_BYTES  = (size_t)ROWS_OUT * sizeof(int);        // 128 KB
constexpr size_t ENTRIES_BYTES = (size_t)ROWS_OUT * CAP * sizeof(int);  // 4 MB
constexpr size_t WS_NEEDED     = COUNTS_BYTES + ENTRIES_BYTES;

constexpr int TOTAL_BLOCKS  = 16384;
constexpr int GATHER_BLOCKS = TOTAL_BLOCKS / 8;                // 2048 (x16 rows)
constexpr int COPY_BLOCKS   = TOTAL_BLOCKS - GATHER_BLOCKS;    // 14336
constexpr size_t COPY_STRIDE = (size_t)COPY_BLOCKS * 256;      // 3,670,016 vec4

// ---- index build (tiny prologue dispatches) -----------------------------------

__global__ void build_index_kernel(const int* __restrict__ idx,
                                   int* __restrict__ counts,
                                   int* __restrict__ entries) {
    const int i = blockIdx.x * blockDim.x + threadIdx.x;   // 0..16383
    const int b = i >> 11;                                  // / N_OLD
    const int bin = (b << 12) + idx[i];                     // b*N_NEW + node
    const int pos = atomicAdd(&counts[bin], 1);
    if (pos < CAP) entries[bin * CAP + pos] = i;            // global X row id
}

// ---- fused: 1:7 interleaved gather / streaming copy ---------------------------

__global__ __launch_bounds__(256) void fused_gather_copy_kernel(
        const f32x4* __restrict__ X4,
        const f32x4* __restrict__ A4,
        const int*   __restrict__ counts,
        const int*   __restrict__ entries,
        f32x4* __restrict__ newX4,
        f32x4* __restrict__ Aout4) {
    const int j = blockIdx.x & 7;
    if (j == 0) {
        // gather block: 16 output rows (4 per wave, sequential)
        const int gid  = blockIdx.x >> 3;              // 0..2047
        const int wave = threadIdx.x >> 6;
        const int lane = threadIdx.x & 63;
        #pragma unroll
        for (int r = 0; r < 4; ++r) {
            const int row = gid * 16 + wave * 4 + r;   // 0..32767, exact cover
            int c = counts[row];
            if (c > CAP) c = CAP;
            f32x4 acc = (f32x4)(0.f);
            const int* e = &entries[(size_t)row * CAP];
            for (int k = 0; k < c; ++k)
                acc += X4[(size_t)e[k] * 64 + lane];   // coalesced 1 KB row
            __builtin_nontemporal_store(acc, &newX4[(size_t)row * 64 + lane]);
        }
    } else {
        // copy block: minimal streaming loop, ~9-10 vec4 iters/thread
        const size_t cid = (size_t)(blockIdx.x >> 3) * 7 + (j - 1); // 0..14335
        size_t i = cid * 256 + threadIdx.x;
        #pragma unroll 2
        for (; i < A_VEC4; i += COPY_STRIDE) {
            const f32x4 v = __builtin_nontemporal_load(&A4[i]);
            __builtin_nontemporal_store(v, &Aout4[i]);
        }
    }
}

// ---- fallback (round-0 proven) ------------------------------------------------

__global__ void zero_newx_kernel(float4* __restrict__ p, size_t n4) {
    size_t i = (size_t)blockIdx.x * blockDim.x + threadIdx.x;
    size_t stride = (size_t)gridDim.x * blockDim.x;
    const float4 z = make_float4(0.f, 0.f, 0.f, 0.f);
    for (; i < n4; i += stride) p[i] = z;
}

__global__ void scatter_add_kernel(const float* __restrict__ X,
                                   const int* __restrict__ idx,
                                   float* __restrict__ out) {
    const int row = blockIdx.x;
    const int f   = threadIdx.x;
    const int b   = row / N_OLD;
    const int node = idx[row];
    const float v = X[(size_t)row * F_ + f];
    atomicAdd(&out[((size_t)b * N_NEW + node) * (size_t)F_ + f], v);
}

extern "C" void kernel_launch(void* const* d_in, const int* in_sizes, int n_in,
                              void* d_out, int out_size, void* d_ws, size_t ws_size,
                              hipStream_t stream) {
    const float* X   = (const float*)d_in[0];
    const float* A   = (const float*)d_in[1];
    const int*   idx = (const int*)d_in[2];

    float* newX  = (float*)d_out;
    float* A_out = (float*)d_out + NEWX_ELEMS;

    if (ws_size >= WS_NEEDED) {
        int* counts  = (int*)d_ws;
        int* entries = (int*)((char*)d_ws + COUNTS_BYTES);

        // counts must be zero every call (graph replays; ws poisoned once)
        (void)hipMemsetAsync(counts, 0, COUNTS_BYTES, stream);

        build_index_kernel<<<ROWS_IN / 256, 256, 0, stream>>>(idx, counts, entries);

        fused_gather_copy_kernel<<<TOTAL_BLOCKS, 256, 0, stream>>>(
            (const f32x4*)X, (const f32x4*)A, counts, entries,
            (f32x4*)newX, (f32x4*)A_out);
    } else {
        zero_newx_kernel<<<2048, 256, 0, stream>>>((float4*)newX, NEWX_ELEMS / 4);
        scatter_add_kernel<<<ROWS_IN, 256, 0, stream>>>(X, idx, newX);
        (void)hipMemcpyAsync(A_out, A, A_ELEMS * sizeof(float),
                             hipMemcpyDeviceToDevice, stream);
    }
}